// Round 6
// baseline (616.063 us; speedup 1.0000x reference)
//
#include <hip/hip_runtime.h>
#include <math.h>

#define HWPX  16384
#define LSTR  67

#define P_OFF     0
#define P_SZ      (8*192*16384)
#define FILT_OFF  (P_OFF + P_SZ)
#define FILT_SZ   (3*192*128*65*2)
#define GS_OFF    (FILT_OFF + FILT_SZ)     // 768 floats
#define SS_OFF    (GS_OFF + 768)           // 384 floats
#define CNT_OFF   (SS_OFF + 384)           // 8 float slots (cnt + pad) -- INSIDE zero range
#define R_OFF     (CNT_OFF + 8)            // 4608 floats
#define W1B_OFF   (R_OFF + 4608)
#define W2B_OFF   (W1B_OFF + 23040)

typedef __attribute__((ext_vector_type(8))) short short8_t;
typedef __attribute__((ext_vector_type(4))) float float4_t;

__device__ __forceinline__ unsigned short bf16_rne(float f){
  unsigned u = __float_as_uint(f);
  unsigned r = (u + 0x7FFFu + ((u>>16)&1u)) >> 16;
  return (unsigned short)r;
}
__device__ __forceinline__ float bf16_to_f(unsigned short h){
  return __uint_as_float(((unsigned)h) << 16);
}

// =====================================================================
// K1 = filt (1536 blocks) + prep (36 blocks) + zero accumulators+cnt
// =====================================================================
__device__ __forceinline__ float cubicw(float tt){
  float t = fabsf(tt), t2=t*t, t3=t2*t;
  if (t <= 1.f) return 1.25f*t3 - 2.25f*t2 + 1.f;
  if (t < 2.f)  return -0.75f*t3 + 3.75f*t2 - 6.f*t + 3.f;
  return 0.f;
}

__global__ __launch_bounds__(256) void k_setup(
    const float* __restrict__ w1, const float* __restrict__ sp_w,
    const float* __restrict__ w2,
    const float* __restrict__ cw0, const float* __restrict__ cw1,
    const float* __restrict__ cw2,
    unsigned short* __restrict__ W1B, unsigned short* __restrict__ W2B,
    float* __restrict__ filt, float* __restrict__ zero_base)
{
  int bx = blockIdx.x;
  int t = threadIdx.x;
  if (bx < 1536) {
    int s = bx >> 9; int idx = bx & 511; int fh = idx >> 2; int mq = idx & 3;
    const float* cw = (s==0) ? cw0 : ((s==1) ? cw1 : cw2);
    int SH = (s==0) ? 16 : ((s==1) ? 8 : 24);
    int SW = (s==0) ? 9  : ((s==1) ? 4 : 13);
    float sh = fh * (float)(SH-1) / 127.f;
    int fh0 = (int)floorf(sh);
    float wh[4]; int ih[4];
    #pragma unroll
    for (int k=0;k<4;k++){
      int kk = fh0-1+k;
      wh[k] = cubicw(sh - (float)kk);
      ih[k] = min(max(kk,0), SH-1);
    }
    for (int i = t; i < 48*65; i += 256) {
      int m = mq*48 + i/65, fw = i%65;
      float sw = fw * (float)(SW-1) / 64.f;
      int fw0 = (int)floorf(sw);
      float are=0.f, aim=0.f;
      #pragma unroll
      for (int kb=0;kb<4;kb++){
        int jj = fw0-1+kb;
        float wwb = cubicw(sw - (float)jj);
        int iw = min(max(jj,0), SW-1);
        #pragma unroll
        for (int ka=0;ka<4;ka++){
          const float* p = cw + (size_t)((ih[ka]*SW + iw)*192 + m)*2;
          float wgt = wh[ka]*wwb;
          are = fmaf(wgt, p[0], are);
          aim = fmaf(wgt, p[1], aim);
        }
      }
      *(float2*)&filt[ (size_t)(((s*192+m)*128 + fh)*65 + fw) * 2 ] = make_float2(are, aim);
    }
  } else {
    int pbx = bx - 1536;
    if (pbx == 0) {
      // zero gsum(768) + ssum(384) + cnt region(8) -- contiguous at zero_base
      for (int i = t; i < 768+384+8; i += 256) zero_base[i] = 0.f;
    }
    int tid = t + pbx*256;
    int nthr = 256*36;
    for (int i = tid; i < 2*3*15*512; i += nthr) {
      int j = i & 7, l = (i>>3) & 63;
      int nt = (i>>9) % 15, kc = ((i>>9)/15) % 3, term = i / (3*15*512);
      int r = nt*16 + (l&15);
      int c = kc*32 + (l>>4)*8 + j;
      float v = (r < 192) ? w1[r*96 + c] : sp_w[(r-192)*96 + c];
      unsigned short hi = bf16_rne(v);
      W1B[i] = (term==0) ? hi : bf16_rne(v - bf16_to_f(hi));
    }
    for (int i = tid; i < 2*6*6*512; i += nthr) {
      int j = i & 7, l = (i>>3) & 63;
      int nt = (i>>9) % 6, kc = ((i>>9)/6) % 6, term = i / (6*6*512);
      int cp = nt*16 + (l&15);
      int mm = kc*32 + (l>>4)*8 + j;
      float v = w2[cp*192 + mm];
      unsigned short hi = bf16_rne(v);
      W2B[i] = (term==0) ? hi : bf16_rne(v - bf16_to_f(hi));
    }
  }
}

// =====================================================================
// K2 = pw1 (MFMA + routing stats) + last-block route MLP/softmax
// =====================================================================
__global__ __launch_bounds__(256) void k_pw1(
    const float* __restrict__ x, const unsigned short* __restrict__ W1B,
    const float* __restrict__ soa_scale, const float* __restrict__ soa_bias,
    const float* __restrict__ bn_gamma, const float* __restrict__ bn_beta,
    const float* __restrict__ bn_mean, const float* __restrict__ bn_var,
    const float* __restrict__ fc1, const float* __restrict__ fc2,
    const float* __restrict__ mlp_scale, const float* __restrict__ mlp_bias,
    float* __restrict__ P, float* __restrict__ gsum, float* __restrict__ ssum,
    float* __restrict__ rbuf, unsigned int* __restrict__ cnt)
{
  __shared__ float red[4][144];
  __shared__ float bnA_s[48], bnB_s[48];
  __shared__ int lastFlag;
  int t = threadIdx.x;
  int lane = t & 63, wv = t >> 6;
  if (t < 48) {
    float a = bn_gamma[t] * rsqrtf(bn_var[t] + 1e-5f);
    bnA_s[t] = a; bnB_s[t] = bn_beta[t] - bn_mean[t]*a;
  }
  int px0 = blockIdx.x*64 + wv*16;
  int b = (blockIdx.x*64) >> 14;
  int pxl = px0 & 16383;
  int g = lane >> 4;

  float4_t acc[15];
  #pragma unroll
  for (int nt=0; nt<15; ++nt) acc[nt] = (float4_t){0.f,0.f,0.f,0.f};

  #pragma unroll
  for (int kc=0; kc<3; ++kc) {
    const float* xp = x + (size_t)(px0 + (lane&15))*96 + kc*32 + g*8;
    float4 v0 = *(const float4*)xp;
    float4 v1 = *(const float4*)(xp+4);
    float vv[8] = {v0.x,v0.y,v0.z,v0.w, v1.x,v1.y,v1.z,v1.w};
    #pragma unroll
    for (int j=0;j<8;j++){
      float s = vv[j];
      s += __shfl_xor(s, 1);
      s += __shfl_xor(s, 2);
      s += __shfl_xor(s, 4);
      s += __shfl_xor(s, 8);
      if ((lane & 15) == 0) red[wv][kc*32 + g*8 + j] = s;
    }
    short8_t Bh, Bl;
    #pragma unroll
    for (int j=0;j<8;j++){
      unsigned short h = bf16_rne(vv[j]);
      Bh[j] = (short)h;
      Bl[j] = (short)bf16_rne(vv[j] - bf16_to_f(h));
    }
    const short8_t* a_hi = (const short8_t*)(W1B + (size_t)(0*3+kc)*15*512) + lane;
    const short8_t* a_lo = (const short8_t*)(W1B + (size_t)(1*3+kc)*15*512) + lane;
    #pragma unroll
    for (int nt=0; nt<15; ++nt) {
      short8_t Ah = a_hi[nt*64];
      short8_t Al = a_lo[nt*64];
      acc[nt] = __builtin_amdgcn_mfma_f32_16x16x32_bf16(Ah, Bh, acc[nt], 0,0,0);
      acc[nt] = __builtin_amdgcn_mfma_f32_16x16x32_bf16(Ah, Bl, acc[nt], 0,0,0);
      acc[nt] = __builtin_amdgcn_mfma_f32_16x16x32_bf16(Al, Bh, acc[nt], 0,0,0);
    }
  }
  float sc = soa_scale[0], bi = soa_bias[0];
  #pragma unroll
  for (int nt=0; nt<12; ++nt) {
    #pragma unroll
    for (int q=0;q<4;q++){
      float d = acc[nt][q];
      float v = fmaxf(d, 0.f);
      d = sc*v*v + bi;
      int mp = nt*16 + g*4 + q;
      P[(size_t)(b*192 + mp)*HWPX + pxl + (lane&15)] = d;
    }
  }
  #pragma unroll
  for (int tile=0; tile<3; ++tile) {
    #pragma unroll
    for (int q=0;q<4;q++){
      int s = tile*16 + g*4 + q;
      float y = acc[12+tile][q];
      float v = fmaxf(bnA_s[s]*y + bnB_s[s], 0.f);
      v += __shfl_xor(v, 1);
      v += __shfl_xor(v, 2);
      v += __shfl_xor(v, 4);
      v += __shfl_xor(v, 8);
      if ((lane & 15) == 0) red[wv][96 + s] = v;
    }
  }
  __syncthreads();
  if (t < 144) {
    float s = red[0][t] + red[1][t] + red[2][t] + red[3][t];
    if (t < 96) atomicAdd(&gsum[b*96 + t], s);
    else        atomicAdd(&ssum[b*48 + (t-96)], s);
  }
  __threadfence();
  __syncthreads();
  if (t == 0) {
    unsigned int old = atomicAdd(cnt, 1u);
    lastFlag = (old == 2047u) ? 1 : 0;
  }
  __syncthreads();
  if (!lastFlag) return;
  __threadfence();   // acquire: see all other blocks' sum atomics

  __shared__ float fused[144], hmid[36], rpre[576];
  float msc = mlp_scale[0], mbi = mlp_bias[0];
  for (int bb = 0; bb < 8; ++bb) {
    if (t < 96)       fused[t] = atomicAdd(&gsum[bb*96 + t], 0.f) * (1.f/16384.f);
    else if (t < 144) fused[t] = atomicAdd(&ssum[bb*48 + (t-96)], 0.f) * (1.f/16384.f);
    __syncthreads();
    if (t < 36) {
      float a = 0.f;
      for (int i=0;i<144;i++) a = fmaf(fused[i], fc1[t*144+i], a);
      float rr = fmaxf(a, 0.f);
      hmid[t] = msc*rr*rr + mbi;
    }
    __syncthreads();
    for (int o = t; o < 576; o += 256) {
      float a = 0.f;
      for (int j=0;j<36;j++) a = fmaf(hmid[j], fc2[o*36+j], a);
      rpre[o] = a;
    }
    __syncthreads();
    if (t < 192) {
      float v0 = rpre[t], v1 = rpre[192+t], v2 = rpre[384+t];
      float mx = fmaxf(v0, fmaxf(v1, v2));
      float e0 = expf(v0-mx), e1 = expf(v1-mx), e2 = expf(v2-mx);
      float inv = 1.f/(e0+e1+e2);
      rbuf[(bb*3+0)*192+t] = e0*inv;
      rbuf[(bb*3+1)*192+t] = e1*inv;
      rbuf[(bb*3+2)*192+t] = e2*inv;
    }
    __syncthreads();
  }
}

// =====================================================================
// K3 = spectral (round-4 float2 FFT body, b-major mapping)
// =====================================================================
__device__ __forceinline__ float2 c_add(float2 a, float2 b){ return make_float2(a.x+b.x, a.y+b.y); }
__device__ __forceinline__ float2 c_sub(float2 a, float2 b){ return make_float2(a.x-b.x, a.y-b.y); }
__device__ __forceinline__ float2 c_mul(float2 a, float2 w){ return make_float2(a.x*w.x - a.y*w.y, a.x*w.y + a.y*w.x); }
__device__ __forceinline__ float2 c_mulc(float2 a, float2 w){ return make_float2(a.x*w.x + a.y*w.y, a.y*w.x - a.x*w.y); }

__device__ __forceinline__ void dif4(float2* S, const float2* TW,
    int a0, int a1, int a2, int a3, int t1, int t2, int t3)
{
  float2 x0=S[a0], x1=S[a1], x2=S[a2], x3=S[a3];
  float2 u = c_add(x0,x2), d0 = c_sub(x0,x2);
  float2 s = c_add(x1,x3), d1 = c_sub(x1,x3);
  float2 w = c_mul(d0, TW[t1]);
  float2 v = c_mul(d1, TW[t2]);
  float2 t3w = TW[t3];
  S[a0] = c_add(u,s);
  S[a1] = c_mul(c_sub(u,s), t3w);
  S[a2] = c_add(w,v);
  S[a3] = c_mul(c_sub(w,v), t3w);
}

__device__ __forceinline__ void dit4(float2* S, const float2* TW,
    int a0, int a1, int a2, int a3, int tA, int tB, int tC)
{
  float2 x0=S[a0], x1=S[a1], x2=S[a2], x3=S[a3];
  float2 wA = TW[tA];
  float2 x1t = c_mulc(x1, wA), x3t = c_mulc(x3, wA);
  float2 u = c_add(x0,x1t), v = c_sub(x0,x1t);
  float2 s = c_add(x2,x3t), w = c_sub(x2,x3t);
  float2 st = c_mulc(s, TW[tB]);
  float2 wt = c_mulc(w, TW[tC]);
  S[a0] = c_add(u, st);
  S[a2] = c_sub(u, st);
  S[a1] = c_add(v, wt);
  S[a3] = c_sub(v, wt);
}

__global__ __launch_bounds__(512, 4) void k_spectral(
    float* __restrict__ P, const float* __restrict__ filt, const float* __restrict__ r)
{
  __shared__ float2 S[128*LSTR];
  __shared__ float2 TW[64];
  int t = threadIdx.x;
  int bm = blockIdx.x;
  int b = bm / 192; int m = bm % 192;
  float* plane = P + ((size_t)b*192 + m) * HWPX;

  if (t < 64) {
    float ang = -6.283185307179586477f * (float)t / 128.f;
    TW[t] = make_float2(cosf(ang), sinf(ang));
  }
  for (int it = 0; it < 8; ++it) {
    int idx = t + 512*it;
    int h = idx >> 5, j = idx & 31;
    float4 v = ((const float4*)plane)[idx];
    int base = h*LSTR + 2*j;
    S[base]   = make_float2(v.x, v.y);
    S[base+1] = make_float2(v.z, v.w);
  }
  float r0 = r[(b*3+0)*192+m];
  float r1 = r[(b*3+1)*192+m];
  float r2 = r[(b*3+2)*192+m];
  __syncthreads();

  #pragma unroll
  for (int ps = 0; ps < 3; ++ps) {
    const int lh = 5 - 2*ps;
    const int h1 = 1 << lh, h2 = h1 >> 1;
    for (int it = 0; it < 4; ++it) {
      int idx = t + 512*it;
      int g = idx & 15, row = idx >> 4;
      int k = g & (h2-1), blk = g >> (lh-1);
      int base = row*LSTR + blk*(2*h1) + k;
      dif4(S,TW, base, base+h2, base+h1, base+h1+h2,
           k << (6-lh), (k+h2) << (6-lh), k << (7-lh));
    }
    __syncthreads();
  }

  for (int it = 0; it < 9; ++it) {
    int idx = t + 512*it;
    if (idx < 128*33) {
      int row = idx & 127, k = idx >> 7;
      int base = row*LSTR;
      if (k == 0) {
        float2 z = S[base];
        S[base]    = make_float2(z.x + z.y, 0.f);
        S[base+64] = make_float2(z.x - z.y, 0.f);
      } else {
        int a = __brev((unsigned)k) >> 26;
        int bidx = __brev((unsigned)(64-k)) >> 26;
        float2 A = S[base+a], B = S[base+bidx];
        float sr_ = 0.5f*(A.x+B.x), si_ = 0.5f*(A.y-B.y);
        float dr  = 0.5f*(A.x-B.x), di  = 0.5f*(A.y+B.y);
        float2 w = TW[k];
        float tr = w.x*di + w.y*dr;
        float ti = -(w.x*dr - w.y*di);
        S[base+a]    = make_float2(sr_ + tr,  si_ + ti);
        S[base+bidx] = make_float2(sr_ - tr, -si_ + ti);
      }
    }
  }
  __syncthreads();

  #pragma unroll
  for (int ps = 0; ps < 3; ++ps) {
    const int lh = 6 - 2*ps;
    const int h1 = 1 << lh, h2 = h1 >> 1;
    for (int it = 0; it < 5; ++it) {
      int idx = t + 512*it;
      if (idx < 65*32) {
        int g = idx / 65, col = idx - g*65;
        int k = g & (h2-1), blk = g >> (lh-1);
        int p = blk*(2*h1) + k;
        dif4(S,TW, p*LSTR+col, (p+h2)*LSTR+col, (p+h1)*LSTR+col, (p+h1+h2)*LSTR+col,
             k << (6-lh), (k+h2) << (6-lh), k << (7-lh));
      }
    }
    __syncthreads();
  }
  for (int it = 0; it < 9; ++it) {
    int idx = t + 512*it;
    if (idx < 65*64) {
      int j = idx / 65, col = idx - j*65;
      int a0 = (2*j)*LSTR + col, a1 = a0 + LSTR;
      float2 u = S[a0], v = S[a1];
      S[a0] = c_add(u,v); S[a1] = c_sub(u,v);
    }
  }
  __syncthreads();

  {
    const float2* fb0 = (const float2*)filt + (size_t)(0*192+m)*8320;
    const float2* fb1 = (const float2*)filt + (size_t)(1*192+m)*8320;
    const float2* fb2 = (const float2*)filt + (size_t)(2*192+m)*8320;
    const float inv = 1.f/8192.f;
    for (int it = 0; it < 17; ++it) {
      int idx = t + 512*it;
      if (idx < 8320) {
        int fh = idx / 65, fw = idx - fh*65;
        float2 f0 = fb0[idx], f1 = fb1[idx], f2 = fb2[idx];
        float cr = (r0*f0.x + r1*f1.x + r2*f2.x) * inv;
        float ci = (r0*f0.y + r1*f1.y + r2*f2.y) * inv;
        int sh = __brev((unsigned)fh) >> 25;
        int sw = (fw == 64) ? 64 : (__brev((unsigned)fw) >> 26);
        int a = sh*LSTR + sw;
        float2 X = S[a];
        S[a] = make_float2(X.x*cr - X.y*ci, X.x*ci + X.y*cr);
      }
    }
  }
  __syncthreads();

  #pragma unroll
  for (int ps = 0; ps < 3; ++ps) {
    const int la = 2*ps;
    const int h = 1 << la;
    for (int it = 0; it < 5; ++it) {
      int idx = t + 512*it;
      if (idx < 65*32) {
        int g = idx / 65, col = idx - g*65;
        int k = g & (h-1), blk = g >> la;
        int p = blk*(4*h) + k;
        dit4(S,TW, p*LSTR+col, (p+h)*LSTR+col, (p+2*h)*LSTR+col, (p+3*h)*LSTR+col,
             k << (6-la), k << (5-la), (k+h) << (5-la));
      }
    }
    __syncthreads();
  }
  for (int it = 0; it < 9; ++it) {
    int idx = t + 512*it;
    if (idx < 65*64) {
      int k = idx / 65, col = idx - k*65;
      int a0 = k*LSTR + col, a1 = a0 + 64*LSTR;
      float2 u = S[a0], xv = S[a1];
      float2 xt = c_mulc(xv, TW[k]);
      S[a0] = c_add(u,xt); S[a1] = c_sub(u,xt);
    }
  }
  __syncthreads();

  for (int it = 0; it < 9; ++it) {
    int idx = t + 512*it;
    if (idx < 128*33) {
      int row = idx & 127, k = idx >> 7;
      int base = row*LSTR;
      if (k == 0) {
        float ar = S[base].x;
        float cr = S[base+64].x;
        S[base] = make_float2(0.5f*(ar+cr), 0.5f*(ar-cr));
      } else {
        int a = __brev((unsigned)k) >> 26;
        int bidx = __brev((unsigned)(64-k)) >> 26;
        float2 A = S[base+a], B = S[base+bidx];
        float sr_ = 0.5f*(A.x+B.x), si_ = 0.5f*(A.y-B.y);
        float dr  = 0.5f*(A.x-B.x), di  = 0.5f*(A.y+B.y);
        float2 w = TW[k];
        float tr2 = w.y*dr - w.x*di;
        float ti2 = w.x*dr + w.y*di;
        S[base+a]    = make_float2(sr_ + tr2,  si_ + ti2);
        S[base+bidx] = make_float2(sr_ - tr2, -si_ + ti2);
      }
    }
  }
  __syncthreads();

  #pragma unroll
  for (int ps = 0; ps < 3; ++ps) {
    const int la = 2*ps;
    const int h = 1 << la;
    for (int it = 0; it < 4; ++it) {
      int idx = t + 512*it;
      int g = idx & 15, row = idx >> 4;
      int k = g & (h-1), blk = g >> la;
      int base = row*LSTR + blk*(4*h) + k;
      dit4(S,TW, base, base+h, base+2*h, base+3*h,
           k << (6-la), k << (5-la), (k+h) << (5-la));
    }
    __syncthreads();
  }

  for (int it = 0; it < 8; ++it) {
    int idx = t + 512*it;
    int h = idx >> 5, j = idx & 31;
    int base = h*LSTR + 2*j;
    float2 z0 = S[base], z1 = S[base+1];
    float4 v; v.x = z0.x; v.y = z0.y; v.z = z1.x; v.w = z1.y;
    ((float4*)plane)[idx] = v;
  }
}

// =====================================================================
// K4 = pw2 (MFMA)
// =====================================================================
__global__ __launch_bounds__(256) void k_pw2(
    const float* __restrict__ P, const unsigned short* __restrict__ W2B,
    float* __restrict__ out)
{
  int t = threadIdx.x;
  int lane = t & 63, wv = t >> 6;
  int px0 = blockIdx.x*64 + wv*16;
  int b = px0 >> 14;
  int pxl = px0 & 16383;

  float4_t acc[6];
  #pragma unroll
  for (int nt=0; nt<6; ++nt) acc[nt] = (float4_t){0.f,0.f,0.f,0.f};

  #pragma unroll
  for (int kc=0; kc<6; ++kc) {
    const float* ap = P + (size_t)(b*192 + kc*32 + (lane>>4)*8)*HWPX + pxl + (lane&15);
    short8_t Ah, Al;
    #pragma unroll
    for (int j=0;j<8;j++){
      float v = ap[(size_t)j*HWPX];
      unsigned short h = bf16_rne(v);
      Ah[j] = (short)h;
      Al[j] = (short)bf16_rne(v - bf16_to_f(h));
    }
    const short8_t* b_hi = (const short8_t*)(W2B + (size_t)(0*6+kc)*6*512) + lane;
    const short8_t* b_lo = (const short8_t*)(W2B + (size_t)(1*6+kc)*6*512) + lane;
    #pragma unroll
    for (int nt=0; nt<6; ++nt) {
      short8_t Bh = b_hi[nt*64];
      short8_t Bl = b_lo[nt*64];
      acc[nt] = __builtin_amdgcn_mfma_f32_16x16x32_bf16(Ah, Bh, acc[nt], 0,0,0);
      acc[nt] = __builtin_amdgcn_mfma_f32_16x16x32_bf16(Ah, Bl, acc[nt], 0,0,0);
      acc[nt] = __builtin_amdgcn_mfma_f32_16x16x32_bf16(Al, Bh, acc[nt], 0,0,0);
    }
  }
  #pragma unroll
  for (int nt=0; nt<6; ++nt) {
    #pragma unroll
    for (int q=0;q<4;q++){
      int px = px0 + (lane>>4)*4 + q;
      out[(size_t)px*96 + nt*16 + (lane&15)] = acc[nt][q];
    }
  }
}

// =====================================================================
extern "C" void kernel_launch(void* const* d_in, const int* in_sizes, int n_in,
                              void* d_out, int out_size, void* d_ws, size_t ws_size,
                              hipStream_t stream) {
  const float* x          = (const float*)d_in[0];
  const float* w1         = (const float*)d_in[1];
  const float* soa1_scale = (const float*)d_in[2];
  const float* soa1_bias  = (const float*)d_in[3];
  const float* cw0        = (const float*)d_in[4];
  const float* cw1        = (const float*)d_in[5];
  const float* cw2        = (const float*)d_in[6];
  const float* sp_w       = (const float*)d_in[7];
  const float* bn_gamma   = (const float*)d_in[8];
  const float* bn_beta    = (const float*)d_in[9];
  const float* bn_mean    = (const float*)d_in[10];
  const float* bn_var     = (const float*)d_in[11];
  const float* fc1        = (const float*)d_in[12];
  const float* mlp_scale  = (const float*)d_in[13];
  const float* mlp_bias   = (const float*)d_in[14];
  const float* fc2        = (const float*)d_in[15];
  const float* w2         = (const float*)d_in[16];
  float* out = (float*)d_out;

  float* ws   = (float*)d_ws;
  float* P    = ws + P_OFF;
  float* filt = ws + FILT_OFF;
  float* gsum = ws + GS_OFF;
  float* ssum = ws + SS_OFF;
  float* rbuf = ws + R_OFF;
  unsigned int* cnt = (unsigned int*)(ws + CNT_OFF);
  unsigned short* W1B = (unsigned short*)(ws + W1B_OFF);
  unsigned short* W2B = (unsigned short*)(ws + W2B_OFF);

  k_setup  <<<1572, 256, 0, stream>>>(w1, sp_w, w2, cw0, cw1, cw2, W1B, W2B, filt, gsum);
  k_pw1    <<<2048, 256, 0, stream>>>(x, W1B, soa1_scale, soa1_bias,
                                      bn_gamma, bn_beta, bn_mean, bn_var,
                                      fc1, fc2, mlp_scale, mlp_bias,
                                      P, gsum, ssum, rbuf, cnt);
  k_spectral<<<1536,512, 0, stream>>>(P, filt, rbuf);
  k_pw2    <<<2048, 256, 0, stream>>>(P, W2B, out);
}